// Round 2
// baseline (164.750 us; speedup 1.0000x reference)
//
#include <hip/hip_runtime.h>

// ForwardDistance: out[b,n,m] = sum_a agg[a] * tanh(datalin[b,n,a] + critlin[b,m,a])
// Identity: tanh(x+y) = 1 - 2/(1 + e^{2x} e^{2y})
// Phase 1: fp32 GEMM on vector ALU (no fp32 MFMA), no LDS: A-rows are wave-uniform
//   (scalarized s_load), B rows coalesced dwordx4 from L2. Fused exp2 epilogue with
//   exponent clamp +-15 (log2 units) -> Ed,Ec <= 2^15, stored transposed in ws.
// Phase 2: quad-grouped reciprocal: sum_{u=0..3} 2agg_u/q_u = N/D, one v_rcp per
//   4 a-terms. q <= 1+2^30 so D <= 2^120 (no overflow). 1024 blocks = 4/CU.

#define A_DIM 256
#define K_DIM 512
#define NROWS 2048   // rows per source (B*N == B*M)

__global__ __launch_bounds__(256) void proj_exp_kernel(
    const float* __restrict__ data, const float* __restrict__ crit,
    const float* __restrict__ Wl, const float* __restrict__ bl,
    const float* __restrict__ Wr, const float* __restrict__ br,
    float* __restrict__ ws)
{
    const int t    = threadIdx.x;
    const int lane = t & 63;
    const int wave = __builtin_amdgcn_readfirstlane(t >> 6);  // 0..3, wave-uniform
    const int rb   = blockIdx.x * 16;       // global row base (0..4095)
    const int src  = rb >> 11;              // 0 = data, 1 = crit
    const int lr   = rb & 2047;             // row base within source

    const float* X    = src ? crit : data;
    const float* W    = src ? Wr   : Wl;
    const float* bias = src ? br   : bl;
    float* ET = ws + (size_t)src * ((size_t)A_DIM * NROWS);

    // wave-uniform A pointer: 4 rows handled by this wave
    const float* arow = X + (size_t)(lr + wave * 4) * K_DIM;
    const int c0 = lane * 4;                // this lane's 4 output columns
    const float* wp = W + c0;

    float acc[4][4];
#pragma unroll
    for (int i = 0; i < 4; i++)
#pragma unroll
        for (int j = 0; j < 4; j++) acc[i][j] = 0.f;

    float  a[2][4][8];   // [pingpong][row][k]  (uniform -> SGPRs expected)
    float4 bb[2][8];     // [pingpong][k]       (per-lane 4 cols)

#pragma unroll
    for (int i = 0; i < 4; i++)
#pragma unroll
        for (int kk = 0; kk < 8; kk++) a[0][i][kk] = arow[i * K_DIM + kk];
#pragma unroll
    for (int kk = 0; kk < 8; kk++) bb[0][kk] = *(const float4*)(wp + (size_t)kk * A_DIM);

#pragma unroll 2
    for (int k0 = 0; k0 < K_DIM; k0 += 8) {
        const int pp = (k0 >> 3) & 1;
        const int np = pp ^ 1;
        if (k0 + 8 < K_DIM) {       // prefetch next k-chunk
            const int kb = k0 + 8;
#pragma unroll
            for (int i = 0; i < 4; i++)
#pragma unroll
                for (int kk = 0; kk < 8; kk++) a[np][i][kk] = arow[i * K_DIM + kb + kk];
#pragma unroll
            for (int kk = 0; kk < 8; kk++)
                bb[np][kk] = *(const float4*)(wp + (size_t)(kb + kk) * A_DIM);
        }
#pragma unroll
        for (int kk = 0; kk < 8; kk++) {
            const float4 b4 = bb[pp][kk];
            const float bv[4] = {b4.x, b4.y, b4.z, b4.w};
#pragma unroll
            for (int i = 0; i < 4; i++)
#pragma unroll
                for (int j = 0; j < 4; j++)
                    acc[i][j] = fmaf(a[pp][i][kk], bv[j], acc[i][j]);
        }
    }

    // epilogue: E = exp2( clamp( 2*log2(e)*(acc+bias), +-15 ) ), store ET[a][row]
    const float c2 = 2.8853900817779268f;   // 2*log2(e)
    const float4 bv4 = *(const float4*)(bias + c0);
    const float bvv[4] = {bv4.x, bv4.y, bv4.z, bv4.w};
#pragma unroll
    for (int j = 0; j < 4; j++) {
        float4 ev;
        float* pv = &ev.x;
#pragma unroll
        for (int i = 0; i < 4; i++) {
            float v = (acc[i][j] + bvv[j]) * c2;
            v = fminf(fmaxf(v, -15.f), 15.f);   // guarantees q<=1+2^30 in phase 2
            pv[i] = __builtin_amdgcn_exp2f(v);
        }
        *(float4*)(ET + (size_t)(c0 + j) * NROWS + lr + wave * 4) = ev;
    }
}

__global__ __launch_bounds__(256) void tanh_reduce_kernel(
    const float* __restrict__ ws, const float* __restrict__ agg,
    float* __restrict__ out)
{
    const int t  = threadIdx.x;
    const int tx = t & 15;              // m group (4 m's)
    const int ty = t >> 4;              // n group (4 n's)
    const int m0 = blockIdx.x * 64;
    const int n0 = blockIdx.y * 64;
    const int b       = blockIdx.z >> 2;
    const int quarter = blockIdx.z & 3; // 64 a's per block -> 4 blocks/CU
    const int a0 = quarter * 64;

    const float* EdT = ws;                           // [A][2048]
    const float* EcT = ws + (size_t)A_DIM * NROWS;   // [A][2048]
    const int row_n = b * 512 + n0;
    const int row_m = b * 512 + m0;

    __shared__ __align__(16) float Et [64][68];  // [a][n]
    __shared__ __align__(16) float Ect[64][68];  // [a][m]
    __shared__ __align__(16) float aggs[64];     // 2*agg[a]

    // stage: thread t loads 16 floats of each tile (aL = t>>2, 16B seg = t&3)
    {
        const int aL  = t >> 2;
        const int seg = (t & 3) * 16;
#pragma unroll
        for (int r = 0; r < 4; r++) {
            *(float4*)&Et [aL][seg + 4*r] = *(const float4*)(EdT + (size_t)(a0 + aL) * NROWS + row_n + seg + 4*r);
            *(float4*)&Ect[aL][seg + 4*r] = *(const float4*)(EcT + (size_t)(a0 + aL) * NROWS + row_m + seg + 4*r);
        }
        if (t < 64) aggs[t] = 2.0f * agg[a0 + t];
    }
    __syncthreads();

    float acc[4][4];
#pragma unroll
    for (int i = 0; i < 4; i++)
#pragma unroll
        for (int j = 0; j < 4; j++) acc[i][j] = 0.f;
    float sagg = 0.f;

    for (int aq = 0; aq < 16; aq++) {
        const float4 ag = *(const float4*)&aggs[aq * 4];
        sagg += (ag.x + ag.y) + (ag.z + ag.w);
        float ed[4][4], ec[4][4];
#pragma unroll
        for (int u = 0; u < 4; u++) {
            float4 e4 = *(const float4*)&Et [aq * 4 + u][ty * 4];
            float4 c4 = *(const float4*)&Ect[aq * 4 + u][tx * 4];
            ed[u][0] = e4.x; ed[u][1] = e4.y; ed[u][2] = e4.z; ed[u][3] = e4.w;
            ec[u][0] = c4.x; ec[u][1] = c4.y; ec[u][2] = c4.z; ec[u][3] = c4.w;
        }
#pragma unroll
        for (int i = 0; i < 4; i++)
#pragma unroll
            for (int j = 0; j < 4; j++) {
                // q_u = 1 + Ed_u*Ec_u ;  sum_u 2agg_u/q_u = N/D, one rcp per 4 terms
                float q0 = fmaf(ed[0][i], ec[0][j], 1.0f);
                float q1 = fmaf(ed[1][i], ec[1][j], 1.0f);
                float q2 = fmaf(ed[2][i], ec[2][j], 1.0f);
                float q3 = fmaf(ed[3][i], ec[3][j], 1.0f);
                float q01 = q0 * q1, q23 = q2 * q3;
                float n01 = fmaf(ag.x, q1, ag.y * q0);
                float n23 = fmaf(ag.z, q3, ag.w * q2);
                float N   = fmaf(n01, q23, n23 * q01);
                float D   = q01 * q23;                      // <= 2^120, no overflow
                acc[i][j] = fmaf(N, __builtin_amdgcn_rcpf(D), acc[i][j]);
            }
    }

    // partial = sum_{a in quarter} agg[a] - acc    (tanh = 1 - 2/q)
    const float base = 0.5f * sagg;
#pragma unroll
    for (int i = 0; i < 4; i++) {
        const int n = n0 + ty * 4 + i;
        float* orow = out + ((size_t)b * 512 + n) * 512 + m0 + tx * 4;
#pragma unroll
        for (int j = 0; j < 4; j++)
            unsafeAtomicAdd(orow + j, base - acc[i][j]);
    }
}

extern "C" void kernel_launch(void* const* d_in, const int* in_sizes, int n_in,
                              void* d_out, int out_size, void* d_ws, size_t ws_size,
                              hipStream_t stream) {
    const float* data = (const float*)d_in[0];
    const float* crit = (const float*)d_in[1];
    const float* Wl   = (const float*)d_in[2];
    const float* bl   = (const float*)d_in[3];
    const float* Wr   = (const float*)d_in[4];
    const float* br   = (const float*)d_in[5];
    const float* agg  = (const float*)d_in[6];
    float* out = (float*)d_out;
    float* ws  = (float*)d_ws;   // 2 * 256 * 2048 * 4 B = 4 MB

    hipMemsetAsync(d_out, 0, (size_t)out_size * sizeof(float), stream);

    // Phase 1: 4096 row-groups of 16 -> 256 blocks; no LDS, no barriers
    proj_exp_kernel<<<dim3(256), 256, 0, stream>>>(data, crit, Wl, bl, Wr, br, ws);

    // Phase 2: (m-tiles, n-tiles, b*4 + a-quarter) = 8*8*16 = 1024 blocks (4/CU)
    tanh_reduce_kernel<<<dim3(8, 8, 16), 256, 0, stream>>>(ws, agg, out);
}